// Round 1
// baseline (173.734 us; speedup 1.0000x reference)
//
#include <hip/hip_runtime.h>
#include <math.h>

// ---------------------------------------------------------------------------
// Reference takes _lstm4(...)[0] -> only t=0 of the whole stack matters.
// With h0=c0=0 each layer is feed-forward: z = x0 @ Wih^T + b,
// c = sigmoid(i)*tanh(g) (f-gate multiplies c0=0 -> dropped),
// h = tanh(sigmoid(o)*tanh(c)).
//
// R4: SINGLE KERNEL, no prep/transpose, no ws. Dot products are computed
// wave-side: each 16-lane group owns one output dot and splits K across
// lanes, so raw weight rows are read lane-contiguous (coalesced float4 for
// all layers except W1, whose 348B rows force scalar loads). Reduction via
// 4x __shfl_xor; z lands directly in LDS (no split-K partial round-trips).
// Biases prefetched into registers at kernel entry (loads issue early,
// consumed after each layer barrier). 256 blocks (1 row/CU) x 768 threads
// (12 waves, 3/SIMD for latency hiding).
// ---------------------------------------------------------------------------

__device__ __forceinline__ float frcp(float x) { return __builtin_amdgcn_rcpf(x); }
__device__ __forceinline__ float sigm(float x) { return frcp(1.0f + __expf(-x)); }
__device__ __forceinline__ float tanh_f(float x) { return 1.0f - 2.0f * frcp(1.0f + __expf(2.0f * x)); }
__device__ __forceinline__ float cell(float zi, float zg, float zo) {
    float c = sigm(zi) * tanh_f(zg);
    return tanh_f(sigm(zo) * tanh_f(c));
}

__global__ __launch_bounds__(768, 1) void lstm_fused_raw(
    const float* __restrict__ x,
    const float* __restrict__ w1i, const float* __restrict__ b1,
    const float* __restrict__ w2i, const float* __restrict__ b2,
    const float* __restrict__ w3i, const float* __restrict__ b3,
    const float* __restrict__ w4i, const float* __restrict__ b4,
    const float* __restrict__ f1w, const float* __restrict__ f1b,
    const float* __restrict__ f2w, const float* __restrict__ f2b,
    const float* __restrict__ f3w, const float* __restrict__ f3b,
    const float* __restrict__ f4w, const float* __restrict__ f4b,
    float* __restrict__ out)
{
    const int t    = threadIdx.x;
    const int r    = blockIdx.x;              // one batch row per block
    const int lane = t & 63;
    const int wid  = t >> 6;                  // 0..11
    const int dl   = lane >> 4;               // 4 dots per wave pass
    const int kc   = lane & 15;               // 16-way K split

    __shared__ __align__(16) float xs[96];
    __shared__ __align__(16) float zs[768];
    __shared__ __align__(16) float h1s[256];
    __shared__ __align__(16) float h2s[128];
    __shared__ __align__(16) float h3s[64];
    __shared__ __align__(16) float h4s[32];
    __shared__ __align__(16) float a1s[128];
    __shared__ __align__(16) float a2s[64];
    __shared__ __align__(16) float a3s[32];

    // Bias prefetch: loads issue at kernel entry, consumed after barriers.
    // PyTorch gate chunks of b: i=[0,H), f=[H,2H) (dropped), g=[2H,3H), o=[3H,4H)
    float bi1 = 0.f, bg1 = 0.f, bo1 = 0.f;
    float bi2 = 0.f, bg2 = 0.f, bo2 = 0.f, bf1 = 0.f;
    float bi3 = 0.f, bg3 = 0.f, bo3 = 0.f, bf2 = 0.f;
    float bi4 = 0.f, bg4 = 0.f, bo4 = 0.f, bf3 = 0.f;
    if (t < 256) { bi1 = b1[t]; bg1 = b1[512 + t]; bo1 = b1[768 + t]; }
    if (t < 128) { bi2 = b2[t]; bg2 = b2[256 + t]; bo2 = b2[384 + t]; bf1 = f1b[t]; }
    if (t < 64)  { bi3 = b3[t]; bg3 = b3[128 + t]; bo3 = b3[192 + t]; bf2 = f2b[t]; }
    if (t < 32)  { bi4 = b4[t]; bg4 = b4[64 + t];  bo4 = b4[96 + t];  bf3 = f3b[t]; }

    if (t < 87) xs[t] = x[r * 87 + t];        // x[0,:,:] slice, row r
    __syncthreads();

    // ---- LSTM1: 87 -> 256. 768 dots x 87 MACs. Rows are 348B (not 16B
    // aligned) -> scalar loads, lane-contiguous within each 16-group. ----
    {
        #pragma unroll 2
        for (int p = 0; p < 16; ++p) {
            const int d    = wid * 4 + dl + p * 48;        // 0..767
            const int j    = d & 255, gate = d >> 8;       // 0=i,1=g,2=o
            const int row  = (gate == 0) ? j : (gate == 1) ? 512 + j : 768 + j;
            const float* wr = w1i + row * 87;
            float a0 = xs[kc]      * wr[kc];
            float a1 = xs[kc + 16] * wr[kc + 16];
            a0 = fmaf(xs[kc + 32], wr[kc + 32], a0);
            a1 = fmaf(xs[kc + 48], wr[kc + 48], a1);
            a0 = fmaf(xs[kc + 64], wr[kc + 64], a0);
            if (kc < 7) a1 = fmaf(xs[kc + 80], wr[kc + 80], a1);  // 87 = 5*16+7
            float acc = a0 + a1;
            acc += __shfl_xor(acc, 1);
            acc += __shfl_xor(acc, 2);
            acc += __shfl_xor(acc, 4);
            acc += __shfl_xor(acc, 8);
            if (kc == 0) zs[d] = acc;
        }
    }
    __syncthreads();
    if (t < 256) h1s[t] = cell(zs[t] + bi1, zs[256 + t] + bg1, zs[512 + t] + bo1);
    __syncthreads();

    // ---- LSTM2: 256 -> 128. 384 dots x 256 MACs, float4 rows (1KB). ----
    {
        #pragma unroll 2
        for (int p = 0; p < 8; ++p) {
            const int d    = wid * 4 + dl + p * 48;        // 0..383
            const int j    = d & 127, gate = d >> 7;
            const int row  = (gate == 0) ? j : (gate == 1) ? 256 + j : 384 + j;
            const float4* wr = (const float4*)(w2i + row * 256);
            float a0 = 0.f, a1 = 0.f;
            #pragma unroll
            for (int it = 0; it < 4; ++it) {
                const float4 wv = wr[kc + 16 * it];
                const float4 hv = *(const float4*)&h1s[4 * kc + 64 * it];
                a0 = fmaf(hv.x, wv.x, a0);
                a1 = fmaf(hv.y, wv.y, a1);
                a0 = fmaf(hv.z, wv.z, a0);
                a1 = fmaf(hv.w, wv.w, a1);
            }
            float acc = a0 + a1;
            acc += __shfl_xor(acc, 1);
            acc += __shfl_xor(acc, 2);
            acc += __shfl_xor(acc, 4);
            acc += __shfl_xor(acc, 8);
            if (kc == 0) zs[d] = acc;
        }
    }
    __syncthreads();
    if (t < 128) h2s[t] = cell(zs[t] + bi2, zs[128 + t] + bg2, zs[256 + t] + bo2);
    __syncthreads();

    // ---- LSTM3: 128 -> 64. 192 dots x 128 MACs. ----
    {
        #pragma unroll
        for (int p = 0; p < 4; ++p) {
            const int d    = wid * 4 + dl + p * 48;        // 0..191
            const int j    = d & 63, gate = d >> 6;
            const int row  = (gate == 0) ? j : (gate == 1) ? 128 + j : 192 + j;
            const float4* wr = (const float4*)(w3i + row * 128);
            const float4 w0  = wr[kc];
            const float4 w1v = wr[kc + 16];
            const float4 h0  = *(const float4*)&h2s[4 * kc];
            const float4 h1v = *(const float4*)&h2s[64 + 4 * kc];
            float a0 = h0.x * w0.x, a1 = h0.y * w0.y;
            a0 = fmaf(h0.z, w0.z, a0);   a1 = fmaf(h0.w, w0.w, a1);
            a0 = fmaf(h1v.x, w1v.x, a0); a1 = fmaf(h1v.y, w1v.y, a1);
            a0 = fmaf(h1v.z, w1v.z, a0); a1 = fmaf(h1v.w, w1v.w, a1);
            float acc = a0 + a1;
            acc += __shfl_xor(acc, 1);
            acc += __shfl_xor(acc, 2);
            acc += __shfl_xor(acc, 4);
            acc += __shfl_xor(acc, 8);
            if (kc == 0) zs[d] = acc;
        }
    }
    __syncthreads();
    if (t < 64) h3s[t] = cell(zs[t] + bi3, zs[64 + t] + bg3, zs[128 + t] + bo3);
    __syncthreads();

    // ---- LSTM4: 64 -> 32. 96 dots x 64 MACs. ----
    {
        #pragma unroll
        for (int p = 0; p < 2; ++p) {
            const int d    = wid * 4 + dl + p * 48;        // 0..95
            const int j    = d & 31, gate = d >> 5;
            const int row  = (gate == 0) ? j : (gate == 1) ? 64 + j : 96 + j;
            const float4* wr = (const float4*)(w4i + row * 64);
            const float4 wv = wr[kc];
            const float4 hv = *(const float4*)&h3s[4 * kc];
            float a0 = hv.x * wv.x, a1 = hv.y * wv.y;
            a0 = fmaf(hv.z, wv.z, a0); a1 = fmaf(hv.w, wv.w, a1);
            float acc = a0 + a1;
            acc += __shfl_xor(acc, 1);
            acc += __shfl_xor(acc, 2);
            acc += __shfl_xor(acc, 4);
            acc += __shfl_xor(acc, 8);
            if (kc == 0) zs[d] = acc;
        }
    }
    __syncthreads();
    if (t < 32) h4s[t] = cell(zs[t] + bi4, zs[32 + t] + bg4, zs[64 + t] + bo4);
    __syncthreads();

    // ---- FC1: 32 -> 128, relu. 128 dots x 32 MACs, 8-lane K split. ----
    {
        const int dle = lane >> 3, kce = lane & 7;
        #pragma unroll
        for (int p = 0; p < 2; ++p) {
            const int d = wid * 8 + dle + p * 96;          // 0..191 (guard)
            if (d < 128) {
                const float4* wr = (const float4*)(f1w + d * 32);
                const float4 wv = wr[kce];
                const float4 hv = *(const float4*)&h4s[4 * kce];
                float acc = fmaf(hv.x, wv.x,
                            fmaf(hv.y, wv.y,
                            fmaf(hv.z, wv.z, hv.w * wv.w)));
                acc += __shfl_xor(acc, 1);
                acc += __shfl_xor(acc, 2);
                acc += __shfl_xor(acc, 4);
                if (kce == 0) zs[d] = acc;
            }
        }
    }
    __syncthreads();
    if (t < 128) a1s[t] = fmaxf(zs[t] + bf1, 0.0f);
    __syncthreads();

    // ---- FC2: 128 -> 64, relu. 64 dots x 128 MACs. ----
    {
        #pragma unroll
        for (int p = 0; p < 2; ++p) {
            const int d = wid * 4 + dl + p * 48;           // 0..95 (guard)
            if (d < 64) {
                const float4* wr = (const float4*)(f2w + d * 128);
                const float4 w0  = wr[kc];
                const float4 w1v = wr[kc + 16];
                const float4 h0  = *(const float4*)&a1s[4 * kc];
                const float4 h1v = *(const float4*)&a1s[64 + 4 * kc];
                float a0 = h0.x * w0.x, a1 = h0.y * w0.y;
                a0 = fmaf(h0.z, w0.z, a0);   a1 = fmaf(h0.w, w0.w, a1);
                a0 = fmaf(h1v.x, w1v.x, a0); a1 = fmaf(h1v.y, w1v.y, a1);
                a0 = fmaf(h1v.z, w1v.z, a0); a1 = fmaf(h1v.w, w1v.w, a1);
                float acc = a0 + a1;
                acc += __shfl_xor(acc, 1);
                acc += __shfl_xor(acc, 2);
                acc += __shfl_xor(acc, 4);
                acc += __shfl_xor(acc, 8);
                if (kc == 0) zs[d] = acc;
            }
        }
    }
    __syncthreads();
    if (t < 64) a2s[t] = fmaxf(zs[t] + bf2, 0.0f);
    __syncthreads();

    // ---- FC3: 64 -> 32, relu. 32 dots x 64 MACs. ----
    {
        const int d = wid * 4 + dl;                        // 0..47 (guard)
        if (d < 32) {
            const float4* wr = (const float4*)(f3w + d * 64);
            const float4 wv = wr[kc];
            const float4 hv = *(const float4*)&a2s[4 * kc];
            float a0 = hv.x * wv.x, a1 = hv.y * wv.y;
            a0 = fmaf(hv.z, wv.z, a0); a1 = fmaf(hv.w, wv.w, a1);
            float acc = a0 + a1;
            acc += __shfl_xor(acc, 1);
            acc += __shfl_xor(acc, 2);
            acc += __shfl_xor(acc, 4);
            acc += __shfl_xor(acc, 8);
            if (kc == 0) zs[d] = acc;
        }
    }
    __syncthreads();
    if (t < 32) a3s[t] = fmaxf(zs[t] + bf3, 0.0f);
    __syncthreads();

    // ---- FC4: 32 -> 3 ----
    if (t < 3) {
        const float4* wr = (const float4*)(f4w + t * 32);
        float a0 = f4b[t], a1 = 0.f;
        #pragma unroll
        for (int i = 0; i < 8; ++i) {
            const float4 wv = wr[i];
            const float4 hv = *(const float4*)&a3s[4 * i];
            a0 = fmaf(hv.x, wv.x, a0);
            a1 = fmaf(hv.y, wv.y, a1);
            a0 = fmaf(hv.z, wv.z, a0);
            a1 = fmaf(hv.w, wv.w, a1);
        }
        out[r * 3 + t] = a0 + a1;
    }
}

extern "C" void kernel_launch(void* const* d_in, const int* in_sizes, int n_in,
                              void* d_out, int out_size, void* d_ws, size_t ws_size,
                              hipStream_t stream) {
    const float* x   = (const float*)d_in[0];
    const float* w1i = (const float*)d_in[1];
    const float* b1  = (const float*)d_in[3];
    const float* w2i = (const float*)d_in[4];
    const float* b2  = (const float*)d_in[6];
    const float* w3i = (const float*)d_in[7];
    const float* b3  = (const float*)d_in[9];
    const float* w4i = (const float*)d_in[10];
    const float* b4  = (const float*)d_in[12];
    const float* f1w = (const float*)d_in[13];
    const float* f1b = (const float*)d_in[14];
    const float* f2w = (const float*)d_in[15];
    const float* f2b = (const float*)d_in[16];
    const float* f3w = (const float*)d_in[17];
    const float* f3b = (const float*)d_in[18];
    const float* f4w = (const float*)d_in[19];
    const float* f4b = (const float*)d_in[20];

    // Single dispatch: one row per block (1 block/CU), 12 waves/block.
    lstm_fused_raw<<<256, 768, 0, stream>>>(x, w1i, b1, w2i, b2, w3i, b3,
                                            w4i, b4, f1w, f1b, f2w, f2b,
                                            f3w, f3b, f4w, f4b,
                                            (float*)d_out);
}